// Round 1
// baseline (2792.730 us; speedup 1.0000x reference)
//
#include <hip/hip_runtime.h>
#include <stdint.h>

#define EPS 1e-5f

// ---------------------------------------------------------------------------
// K0: P[N x 256] = x[N x 128] @ Wc^T where Wc[j][k] = (j<128) ? W1[j][k]
//                                                            : W1[j-128][128+k]
// So P[n][0:128] = x[n] @ W1a^T (src half), P[n][128:256] = x[n] @ W1b^T (dst half).
// Tiles 64x64, BK=32, 256 threads (16x16), 4x4 per thread. fp32 VALU.
// ---------------------------------------------------------------------------
__global__ __launch_bounds__(256) void gemm_p_kernel(const float* __restrict__ x,
    const float* __restrict__ W1, float* __restrict__ P, int Nn)
{
    __shared__ float As[64][36];   // stride 36: 16B-aligned rows, bank shift 4
    __shared__ float Bt[32][68];   // transposed W chunk: Bt[kk][col], 2-way (free) reads
    int tid = threadIdx.x;
    int tx = tid & 15, ty = tid >> 4;
    int m0 = blockIdx.x * 64;
    int n0 = blockIdx.y * 64;
    float acc[4][4] = {};
    for (int kc = 0; kc < 128; kc += 32) {
        for (int t = tid; t < 512; t += 256) {
            int r = t >> 3, q = t & 7;
            int m = m0 + r;
            float4 v = make_float4(0.f, 0.f, 0.f, 0.f);
            if (m < Nn) v = *(const float4*)&x[(size_t)m * 128 + kc + q * 4];
            *(float4*)&As[r][q * 4] = v;
        }
        for (int t = tid; t < 512; t += 256) {
            int r = t >> 3, q = t & 7;      // r = tile col, q*4 = k offset
            int j = n0 + r;
            const float* s = (j < 128) ? &W1[(size_t)j * 256 + kc + q * 4]
                                       : &W1[(size_t)(j - 128) * 256 + 128 + kc + q * 4];
            float4 w = *(const float4*)s;
            Bt[q * 4 + 0][r] = w.x; Bt[q * 4 + 1][r] = w.y;
            Bt[q * 4 + 2][r] = w.z; Bt[q * 4 + 3][r] = w.w;
        }
        __syncthreads();
        #pragma unroll
        for (int kk = 0; kk < 32; kk += 4) {
            float avf[4][4];
            #pragma unroll
            for (int i = 0; i < 4; i++)
                *(float4*)&avf[i][0] = *(const float4*)&As[ty * 4 + i][kk];
            #pragma unroll
            for (int s = 0; s < 4; s++) {
                float4 b = *(const float4*)&Bt[kk + s][tx * 4];
                float bb[4] = {b.x, b.y, b.z, b.w};
                #pragma unroll
                for (int i = 0; i < 4; i++)
                    #pragma unroll
                    for (int j = 0; j < 4; j++)
                        acc[i][j] = fmaf(avf[i][s], bb[j], acc[i][j]);
            }
        }
        __syncthreads();
    }
    #pragma unroll
    for (int i = 0; i < 4; i++) {
        int m = m0 + ty * 4 + i;
        if (m < Nn)
            *(float4*)&P[(size_t)m * 256 + n0 + tx * 4] =
                make_float4(acc[i][0], acc[i][1], acc[i][2], acc[i][3]);
    }
}

// ---------------------------------------------------------------------------
// K1: BN1 batch stats of h1[e][c] = Ps[src[e]][c] + Pd[dst[e]][c]  (b1 dropped:
// BN is invariant to a per-channel constant shift). Per-thread channel-local
// accumulation, block combine, one atomicAdd per channel per block.
// ---------------------------------------------------------------------------
__global__ __launch_bounds__(256) void stats1_kernel(const float* __restrict__ P,
    const int* __restrict__ src, const int* __restrict__ dst, int E,
    float* __restrict__ gsum, float* __restrict__ gsq)
{
    int tid = threadIdx.x;
    int c = tid & 127;
    int rh = tid >> 7;
    float ls = 0.f, lq = 0.f;
    int stride = gridDim.x * 2;
    #pragma unroll 2
    for (int e = blockIdx.x * 2 + rh; e < E; e += stride) {
        int s = src[e], d = dst[e];
        float v = P[(size_t)s * 256 + c] + P[(size_t)d * 256 + 128 + c];
        ls += v; lq += v * v;
    }
    __shared__ float sh[512];
    sh[tid] = ls; sh[256 + tid] = lq;
    __syncthreads();
    if (tid < 128) {
        atomicAdd(&gsum[c], sh[tid] + sh[tid + 128]);
        atomicAdd(&gsq[c], sh[256 + tid] + sh[256 + tid + 128]);
    }
}

// ---------------------------------------------------------------------------
// Finalize BN params: a = gamma / sqrt(var+eps), c = beta - mean*a  (biased var)
// ---------------------------------------------------------------------------
__global__ void finalize_kernel(const float* __restrict__ gsum, const float* __restrict__ gsq,
    const float* __restrict__ gamma, const float* __restrict__ beta, float Einv,
    float* __restrict__ a, float* __restrict__ cc)
{
    int c = threadIdx.x;
    float mean = gsum[c] * Einv;
    float var  = gsq[c] * Einv - mean * mean;
    float ai = gamma[c] / sqrtf(var + EPS);
    a[c] = ai;
    cc[c] = beta[c] - mean * ai;
}

// ---------------------------------------------------------------------------
// K3: per 64-edge tile: U = relu(a1*(Ps[s]+Pd[d]) + c1)  (LDS, 64x132),
// then h2_tile = U @ W2^T (W2 staged transposed per 32-k chunk).
// MODE 0: write h2 + accumulate BN2 stats.   MODE 1: stats only (no h2 buffer).
// MODE 2: recompute + apply BN2+ReLU + scatter atomicAdd (fallback path).
// ---------------------------------------------------------------------------
template<int MODE>
__global__ __launch_bounds__(256) void edge_main_kernel(
    const float* __restrict__ P, const int* __restrict__ src, const int* __restrict__ dst,
    const float* __restrict__ W2, const float* __restrict__ a1, const float* __restrict__ c1,
    float* __restrict__ h2, float* __restrict__ gsum, float* __restrict__ gsq,
    const float* __restrict__ a2, const float* __restrict__ c2,
    float* __restrict__ out, int E)
{
    __shared__ float U[64][132];
    __shared__ float Wt[32][132];   // Wt[kk][c] = W2[c][kc+kk]; aliased as red[] later
    __shared__ int sidx[64], didx[64];
    int tid = threadIdx.x;
    int e0 = blockIdx.x * 64;
    if (tid < 64) {
        int e = min(e0 + tid, E - 1);
        sidx[tid] = src[e];
        didx[tid] = dst[e];
    }
    __syncthreads();
    {   // phase A: gather + BN1 + ReLU into U
        int c = tid & 127, r0 = tid >> 7;
        float a1c = a1[c], c1c = c1[c];
        for (int r = r0; r < 64; r += 2) {
            int s = sidx[r], d = didx[r];
            float v = P[(size_t)s * 256 + c] + P[(size_t)d * 256 + 128 + c];
            U[r][c] = fmaxf(fmaf(a1c, v, c1c), 0.f);
        }
    }
    int tx = tid & 15, ty = tid >> 4;   // thread tile: rows ty*4+[0,4), cols tx*8+[0,8)
    float acc[4][8] = {};
    for (int kc = 0; kc < 128; kc += 32) {
        __syncthreads();   // Wt safe to overwrite (also covers phase-A -> read of U)
        #pragma unroll
        for (int q = 0; q < 4; q++) {
            int f4 = q * 256 + tid;
            int c = f4 >> 3, k4 = (f4 & 7) * 4;
            float4 w = *(const float4*)&W2[(size_t)c * 128 + kc + k4];
            Wt[k4 + 0][c] = w.x; Wt[k4 + 1][c] = w.y;
            Wt[k4 + 2][c] = w.z; Wt[k4 + 3][c] = w.w;
        }
        __syncthreads();
        #pragma unroll
        for (int kk = 0; kk < 32; kk += 4) {
            float avf[4][4];
            #pragma unroll
            for (int i = 0; i < 4; i++)
                *(float4*)&avf[i][0] = *(const float4*)&U[ty * 4 + i][kc + kk];
            #pragma unroll
            for (int s = 0; s < 4; s++) {
                float4 b0 = *(const float4*)&Wt[kk + s][tx * 8];
                float4 b1 = *(const float4*)&Wt[kk + s][tx * 8 + 4];
                float bb[8] = {b0.x, b0.y, b0.z, b0.w, b1.x, b1.y, b1.z, b1.w};
                #pragma unroll
                for (int i = 0; i < 4; i++) {
                    float av = avf[i][s];
                    #pragma unroll
                    for (int j = 0; j < 8; j++)
                        acc[i][j] = fmaf(av, bb[j], acc[i][j]);
                }
            }
        }
    }
    int rmax = E - e0;   // rows valid in this tile (>=1)

    if (MODE == 0) {
        #pragma unroll
        for (int i = 0; i < 4; i++) {
            int r = ty * 4 + i;
            if (r < rmax) {
                size_t off = (size_t)(e0 + r) * 128 + tx * 8;
                *(float4*)&h2[off]     = make_float4(acc[i][0], acc[i][1], acc[i][2], acc[i][3]);
                *(float4*)&h2[off + 4] = make_float4(acc[i][4], acc[i][5], acc[i][6], acc[i][7]);
            }
        }
    }
    if (MODE == 0 || MODE == 1) {
        float s1[8], s2[8];
        #pragma unroll
        for (int j = 0; j < 8; j++) { s1[j] = 0.f; s2[j] = 0.f; }
        #pragma unroll
        for (int i = 0; i < 4; i++) {
            if (ty * 4 + i < rmax) {
                #pragma unroll
                for (int j = 0; j < 8; j++) {
                    float v = acc[i][j];
                    s1[j] += v; s2[j] += v * v;
                }
            }
        }
        // reduce over ty within wave (lane = (ty&3)*16 + tx)
        #pragma unroll
        for (int j = 0; j < 8; j++) {
            s1[j] += __shfl_xor(s1[j], 16); s1[j] += __shfl_xor(s1[j], 32);
            s2[j] += __shfl_xor(s2[j], 16); s2[j] += __shfl_xor(s2[j], 32);
        }
        float* red = &Wt[0][0];   // alias: 8*128 floats <= 32*132
        __syncthreads();          // all Wt reads done
        if ((ty & 3) == 0) {
            int w = ty >> 2;
            #pragma unroll
            for (int j = 0; j < 8; j++) {
                int c = tx * 8 + j;
                red[w * 128 + c]       = s1[j];
                red[(4 + w) * 128 + c] = s2[j];
            }
        }
        __syncthreads();
        if (tid < 128) {
            float t1 = red[tid] + red[128 + tid] + red[256 + tid] + red[384 + tid];
            float t2 = red[512 + tid] + red[640 + tid] + red[768 + tid] + red[896 + tid];
            atomicAdd(&gsum[tid], t1);
            atomicAdd(&gsq[tid], t2);
        }
    }
    if (MODE == 2) {
        float a2v[8], c2v[8];
        #pragma unroll
        for (int j = 0; j < 8; j++) { a2v[j] = a2[tx * 8 + j]; c2v[j] = c2[tx * 8 + j]; }
        #pragma unroll
        for (int i = 0; i < 4; i++) {
            int r = ty * 4 + i;
            if (r < rmax) {
                int dn = didx[r];
                #pragma unroll
                for (int j = 0; j < 8; j++) {
                    float y = fmaxf(fmaf(a2v[j], acc[i][j], c2v[j]), 0.f);
                    if (y > 0.f) atomicAdd(&out[(size_t)dn * 128 + tx * 8 + j], y);
                }
            }
        }
    }
}

// ---------------------------------------------------------------------------
// K5 (materialized path): y = relu(a2*h2 + c2), scatter-add into out[dst]
// ---------------------------------------------------------------------------
__global__ __launch_bounds__(256) void scatter_kernel(const float* __restrict__ h2,
    const int* __restrict__ dst, const float* __restrict__ a2, const float* __restrict__ c2,
    float* __restrict__ out, int E)
{
    int tid = threadIdx.x;
    int c = tid & 127, rh = tid >> 7;
    float ac = a2[c], cc = c2[c];
    int stride = gridDim.x * 2;
    for (int e = blockIdx.x * 2 + rh; e < E; e += stride) {
        float y = fmaxf(fmaf(ac, h2[(size_t)e * 128 + c], cc), 0.f);
        if (y > 0.f) atomicAdd(&out[(size_t)dst[e] * 128 + c], y);
    }
}

// ---------------------------------------------------------------------------
extern "C" void kernel_launch(void* const* d_in, const int* in_sizes, int n_in,
                              void* d_out, int out_size, void* d_ws, size_t ws_size,
                              hipStream_t stream)
{
    const float* x   = (const float*)d_in[0];
    const int*   ei  = (const int*)d_in[1];
    const float* W1  = (const float*)d_in[2];
    // d_in[3] = b1: unused (BN shift-invariance)
    const float* g1  = (const float*)d_in[4];
    const float* be1 = (const float*)d_in[5];
    const float* W2  = (const float*)d_in[6];
    // d_in[7] = b2: unused
    const float* g2  = (const float*)d_in[8];
    const float* be2 = (const float*)d_in[9];
    float* out = (float*)d_out;

    int Nn = in_sizes[0] / 128;
    int E  = in_sizes[1] / 2;
    const int* srcI = ei;
    const int* dstI = ei + E;

    float* ws    = (float*)d_ws;
    float* gsum1 = ws;        float* gsq1 = ws + 128;
    float* gsum2 = ws + 256;  float* gsq2 = ws + 384;
    float* a1    = ws + 512;  float* c1   = ws + 640;
    float* a2    = ws + 768;  float* c2   = ws + 896;
    float* P     = ws + 1024;
    float* h2    = P + (size_t)Nn * 256;
    size_t need_mat = (1024 + (size_t)Nn * 256 + (size_t)E * 128) * sizeof(float);
    bool mat = (ws_size >= need_mat);

    hipMemsetAsync(ws, 0, 512 * sizeof(float), stream);            // stats accumulators
    hipMemsetAsync(out, 0, (size_t)out_size * sizeof(float), stream);

    dim3 b256(256);
    gemm_p_kernel<<<dim3((Nn + 63) / 64, 4), b256, 0, stream>>>(x, W1, P, Nn);
    stats1_kernel<<<2048, b256, 0, stream>>>(P, srcI, dstI, E, gsum1, gsq1);
    finalize_kernel<<<1, 128, 0, stream>>>(gsum1, gsq1, g1, be1, 1.0f / (float)E, a1, c1);

    int gE = (E + 63) / 64;
    if (mat) {
        edge_main_kernel<0><<<gE, b256, 0, stream>>>(P, srcI, dstI, W2, a1, c1,
            h2, gsum2, gsq2, nullptr, nullptr, nullptr, E);
        finalize_kernel<<<1, 128, 0, stream>>>(gsum2, gsq2, g2, be2, 1.0f / (float)E, a2, c2);
        scatter_kernel<<<4096, b256, 0, stream>>>(h2, dstI, a2, c2, out, E);
    } else {
        edge_main_kernel<1><<<gE, b256, 0, stream>>>(P, srcI, dstI, W2, a1, c1,
            nullptr, gsum2, gsq2, nullptr, nullptr, nullptr, E);
        finalize_kernel<<<1, 128, 0, stream>>>(gsum2, gsq2, g2, be2, 1.0f / (float)E, a2, c2);
        edge_main_kernel<2><<<gE, b256, 0, stream>>>(P, srcI, dstI, W2, a1, c1,
            nullptr, nullptr, nullptr, a2, c2, out, E);
    }
}

// Round 6
// 2689.185 us; speedup vs baseline: 1.0385x; 1.0385x over previous
//
#include <hip/hip_runtime.h>
#include <stdint.h>

#define EPS 1e-5f

typedef __attribute__((ext_vector_type(4))) float f32x4;
typedef __attribute__((ext_vector_type(8))) short bf16x8_t;

__device__ __forceinline__ unsigned short f2bf(float x) {
    unsigned u = __float_as_uint(x);
    unsigned r = (u + 0x7FFFu + ((u >> 16) & 1u)) >> 16;
    return (unsigned short)r;
}
__device__ __forceinline__ float bf2f(unsigned short b) {
    return __uint_as_float(((unsigned)b) << 16);
}

// ---------------------------------------------------------------------------
// K0: P[N x 256] = x[N x 128] @ Wc^T ; Wc[j] = (j<128) ? W1[j][0:128] : W1[j-128][128:256]
// fp32 VALU, 64x64 tile, BK=32, 256 threads, 4x4/thread.
// ---------------------------------------------------------------------------
__global__ __launch_bounds__(256) void gemm_p_kernel(const float* __restrict__ x,
    const float* __restrict__ W1, float* __restrict__ P, int Nn)
{
    __shared__ float As[64][36];
    __shared__ float Bt[32][68];
    int tid = threadIdx.x;
    int tx = tid & 15, ty = tid >> 4;
    int m0 = blockIdx.x * 64;
    int n0 = blockIdx.y * 64;
    float acc[4][4] = {};
    for (int kc = 0; kc < 128; kc += 32) {
        for (int t = tid; t < 512; t += 256) {
            int r = t >> 3, q = t & 7;
            int m = m0 + r;
            float4 v = make_float4(0.f, 0.f, 0.f, 0.f);
            if (m < Nn) v = *(const float4*)&x[(size_t)m * 128 + kc + q * 4];
            *(float4*)&As[r][q * 4] = v;
        }
        for (int t = tid; t < 512; t += 256) {
            int r = t >> 3, q = t & 7;
            int j = n0 + r;
            const float* s = (j < 128) ? &W1[(size_t)j * 256 + kc + q * 4]
                                       : &W1[(size_t)(j - 128) * 256 + 128 + kc + q * 4];
            float4 w = *(const float4*)s;
            Bt[q * 4 + 0][r] = w.x; Bt[q * 4 + 1][r] = w.y;
            Bt[q * 4 + 2][r] = w.z; Bt[q * 4 + 3][r] = w.w;
        }
        __syncthreads();
        #pragma unroll
        for (int kk = 0; kk < 32; kk += 4) {
            float avf[4][4];
            #pragma unroll
            for (int i = 0; i < 4; i++)
                *(float4*)&avf[i][0] = *(const float4*)&As[ty * 4 + i][kk];
            #pragma unroll
            for (int s = 0; s < 4; s++) {
                float4 b = *(const float4*)&Bt[kk + s][tx * 4];
                float bb[4] = {b.x, b.y, b.z, b.w};
                #pragma unroll
                for (int i = 0; i < 4; i++)
                    #pragma unroll
                    for (int j = 0; j < 4; j++)
                        acc[i][j] = fmaf(avf[i][s], bb[j], acc[i][j]);
            }
        }
        __syncthreads();
    }
    #pragma unroll
    for (int i = 0; i < 4; i++) {
        int m = m0 + ty * 4 + i;
        if (m < Nn)
            *(float4*)&P[(size_t)m * 256 + n0 + tx * 4] =
                make_float4(acc[i][0], acc[i][1], acc[i][2], acc[i][3]);
    }
}

// ---------------------------------------------------------------------------
// W2 -> bf16 (once per call)
// ---------------------------------------------------------------------------
__global__ void convert_w2_kernel(const float* __restrict__ W2, unsigned short* __restrict__ W2bf)
{
    int i = blockIdx.x * 256 + threadIdx.x;   // grid 64 -> 16384 threads
    W2bf[i] = f2bf(W2[i]);
}

// ---------------------------------------------------------------------------
// K1: BN1 stats of h1[e][c] = Ps[src[e]][c] + Pd[dst[e]][c]. (b1 dropped: BN shift-inv.)
// ---------------------------------------------------------------------------
__global__ __launch_bounds__(256) void stats1_kernel(const float* __restrict__ P,
    const int* __restrict__ src, const int* __restrict__ dst, int E,
    float* __restrict__ gsum, float* __restrict__ gsq)
{
    int tid = threadIdx.x;
    int cg = tid & 31, rg = tid >> 5;
    int c0 = cg * 4;
    f32x4 s = {0.f, 0.f, 0.f, 0.f}, q = {0.f, 0.f, 0.f, 0.f};
    int stride = gridDim.x * 8;
    for (int e = blockIdx.x * 8 + rg; e < E; e += stride) {
        int sN = src[e], dN = dst[e];
        f32x4 v = *(const f32x4*)&P[(size_t)sN * 256 + c0]
                + *(const f32x4*)&P[(size_t)dN * 256 + 128 + c0];
        s += v; q += v * v;
    }
    __shared__ float shs[8][128], shq[8][128];
    *(f32x4*)&shs[rg][c0] = s;
    *(f32x4*)&shq[rg][c0] = q;
    __syncthreads();
    if (tid < 128) {
        float ts = 0.f, tq = 0.f;
        #pragma unroll
        for (int g = 0; g < 8; g++) { ts += shs[g][tid]; tq += shq[g][tid]; }
        atomicAdd(&gsum[tid], ts);
        atomicAdd(&gsq[tid], tq);
    }
}

// ---------------------------------------------------------------------------
// Finalize BN: a = gamma*rsqrt(var+eps), c = beta - mean*a (biased var)
// ---------------------------------------------------------------------------
__global__ void finalize_kernel(const float* __restrict__ gsum, const float* __restrict__ gsq,
    const float* __restrict__ gamma, const float* __restrict__ beta, float Einv,
    float* __restrict__ a, float* __restrict__ cc)
{
    int c = threadIdx.x;
    float mean = gsum[c] * Einv;
    float var  = gsq[c] * Einv - mean * mean;
    float ai = gamma[c] / sqrtf(var + EPS);
    a[c] = ai;
    cc[c] = beta[c] - mean * ai;
}

// ---------------------------------------------------------------------------
// K3: MFMA edge GEMM2. Per block: 64 edges x 128 cols. 4 waves (2m x 2n).
// A = U = relu(a1*(Ps[s]+Pd[d])+c1) gathered straight into MFMA A-frags
// (reg-only K-loop, no barriers). U split hi+lo bf16; W2 bf16 (L2-resident).
// Slot->k mapping is the same permutation for A and B, so D = U @ W2^T exactly.
// MODE 0: write h2(bf16) + BN2 stats.  MODE 1: stats only.  MODE 2: BN2+ReLU+scatter.
// ---------------------------------------------------------------------------
template<int MODE>
__global__ __launch_bounds__(256) void edge_mfma_kernel(
    const float* __restrict__ P, const int* __restrict__ src, const int* __restrict__ dst,
    const unsigned short* __restrict__ W2bf,
    const float* __restrict__ a1, const float* __restrict__ c1,
    unsigned short* __restrict__ h2, float* __restrict__ gsum, float* __restrict__ gsq,
    const float* __restrict__ a2, const float* __restrict__ c2,
    float* __restrict__ out, int E)
{
    int tid = threadIdx.x;
    int wid = tid >> 6, lane = tid & 63;
    int lr = lane & 15, lk = lane >> 4;        // A row / B col = lr, k-group = lk
    int wm = wid >> 1, wn = wid & 1;
    int e0 = blockIdx.x * 64;
    int m0w = wm * 32, n0w = wn * 64;

    __shared__ int didx[64];                   // dst per tile row (MODE 2 epilogue)
    if (MODE == 2 && tid < 64) {
        int e = min(e0 + tid, E - 1);
        didx[tid] = dst[e];
    }

    int e_mi[2], s_mi[2], d_mi[2];
    #pragma unroll
    for (int mi = 0; mi < 2; mi++) {
        int e = e0 + m0w + mi * 16 + lr;
        e_mi[mi] = e;
        int ec = min(e, E - 1);
        s_mi[mi] = src[ec];
        d_mi[mi] = dst[ec];
    }

    f32x4 acc[2][4];
    #pragma unroll
    for (int mi = 0; mi < 2; mi++)
        #pragma unroll
        for (int nj = 0; nj < 4; nj++) {
            f32x4 z = {0.f, 0.f, 0.f, 0.f};
            acc[mi][nj] = z;
        }

    #pragma unroll
    for (int kt = 0; kt < 4; kt++) {
        int c0 = kt * 32 + lk * 8;
        bf16x8_t b[4];
        #pragma unroll
        for (int nj = 0; nj < 4; nj++)
            b[nj] = *(const bf16x8_t*)&W2bf[(size_t)(n0w + nj * 16 + lr) * 128 + c0];
        f32x4 a1v0 = *(const f32x4*)&a1[c0], a1v1 = *(const f32x4*)&a1[c0 + 4];
        f32x4 c1v0 = *(const f32x4*)&c1[c0], c1v1 = *(const f32x4*)&c1[c0 + 4];
        #pragma unroll
        for (int mi = 0; mi < 2; mi++) {
            const float* ps = &P[(size_t)s_mi[mi] * 256 + c0];
            const float* pd = &P[(size_t)d_mi[mi] * 256 + 128 + c0];
            f32x4 h0 = *(const f32x4*)ps + *(const f32x4*)pd;
            f32x4 h1 = *(const f32x4*)(ps + 4) + *(const f32x4*)(pd + 4);
            float vm = (e_mi[mi] < E) ? 1.f : 0.f;
            bf16x8_t ahi, alo;
            #pragma unroll
            for (int j = 0; j < 8; j++) {
                float hv = (j < 4) ? h0[j] : h1[j - 4];
                float av = (j < 4) ? a1v0[j] : a1v1[j - 4];
                float cv = (j < 4) ? c1v0[j] : c1v1[j - 4];
                float u = fmaxf(fmaf(av, hv, cv), 0.f) * vm;
                unsigned short uh = f2bf(u);
                ahi[j] = (short)uh;
                alo[j] = (short)f2bf(u - bf2f(uh));
            }
            #pragma unroll
            for (int nj = 0; nj < 4; nj++) {
                acc[mi][nj] = __builtin_amdgcn_mfma_f32_16x16x32_bf16(ahi, b[nj], acc[mi][nj], 0, 0, 0);
                acc[mi][nj] = __builtin_amdgcn_mfma_f32_16x16x32_bf16(alo, b[nj], acc[mi][nj], 0, 0, 0);
            }
        }
    }
    // D layout (m89-verified): col = lane&15 (=lr), row = lk*4 + reg.

    if (MODE == 0 || MODE == 1) {
        __shared__ float reds[2][128], redq[2][128];
        #pragma unroll
        for (int nj = 0; nj < 4; nj++) {
            float sa = 0.f, sq = 0.f;
            #pragma unroll
            for (int mi = 0; mi < 2; mi++)
                #pragma unroll
                for (int r = 0; r < 4; r++) {
                    float v = acc[mi][nj][r];
                    sa += v; sq += v * v;
                }
            sa += __shfl_xor(sa, 16); sa += __shfl_xor(sa, 32);
            sq += __shfl_xor(sq, 16); sq += __shfl_xor(sq, 32);
            if (lk == 0) {
                reds[wm][n0w + nj * 16 + lr] = sa;
                redq[wm][n0w + nj * 16 + lr] = sq;
            }
        }
        if (MODE == 0) {
            __shared__ unsigned short ush[64][136];
            #pragma unroll
            for (int mi = 0; mi < 2; mi++)
                #pragma unroll
                for (int nj = 0; nj < 4; nj++)
                    #pragma unroll
                    for (int r = 0; r < 4; r++)
                        ush[m0w + mi * 16 + lk * 4 + r][n0w + nj * 16 + lr] = f2bf(acc[mi][nj][r]);
            __syncthreads();
            if (tid < 128) {
                atomicAdd(&gsum[tid], reds[0][tid] + reds[1][tid]);
                atomicAdd(&gsq[tid],  redq[0][tid] + redq[1][tid]);
            }
            // 64 rows x 16 bf16x8 chunks = 1024 chunks; 4 x 256 covers all (r2 bug: wrote 512)
            #pragma unroll
            for (int it = 0; it < 4; it++) {
                int chunk = it * 256 + tid;
                int row = chunk >> 4, q = chunk & 15;
                bf16x8_t v = *(const bf16x8_t*)&ush[row][q * 8];
                if (e0 + row < E)
                    *(bf16x8_t*)&h2[(size_t)(e0 + row) * 128 + q * 8] = v;
            }
        } else {
            __syncthreads();
            if (tid < 128) {
                atomicAdd(&gsum[tid], reds[0][tid] + reds[1][tid]);
                atomicAdd(&gsq[tid],  redq[0][tid] + redq[1][tid]);
            }
        }
    }
    if (MODE == 2) {
        __syncthreads();   // didx visible
        float a2v[4], c2v[4];
        #pragma unroll
        for (int nj = 0; nj < 4; nj++) {
            int col = n0w + nj * 16 + lr;
            a2v[nj] = a2[col]; c2v[nj] = c2[col];
        }
        #pragma unroll
        for (int mi = 0; mi < 2; mi++)
            #pragma unroll
            for (int r = 0; r < 4; r++) {
                int row = m0w + mi * 16 + lk * 4 + r;
                if (e0 + row < E) {
                    int dn = didx[row];
                    #pragma unroll
                    for (int nj = 0; nj < 4; nj++) {
                        float y = fmaxf(fmaf(a2v[nj], acc[mi][nj][r], c2v[nj]), 0.f);
                        if (y > 0.f) atomicAdd(&out[(size_t)dn * 128 + n0w + nj * 16 + lr], y);
                    }
                }
            }
    }
}

// ---------------------------------------------------------------------------
// K5: y = relu(a2*h2 + c2), scatter-add into out[dst]; bf16 h2, pruned atomics
// ---------------------------------------------------------------------------
__global__ __launch_bounds__(256) void scatter_kernel(const unsigned short* __restrict__ h2,
    const int* __restrict__ dst, const float* __restrict__ a2, const float* __restrict__ c2,
    float* __restrict__ out, int E)
{
    int tid = threadIdx.x;
    int cg = tid & 15, rg = tid >> 4;
    int c0 = cg * 8;
    float av[8], cv[8];
    #pragma unroll
    for (int j = 0; j < 8; j++) { av[j] = a2[c0 + j]; cv[j] = c2[c0 + j]; }
    int stride = gridDim.x * 16;
    for (int e = blockIdx.x * 16 + rg; e < E; e += stride) {
        bf16x8_t hv = *(const bf16x8_t*)&h2[(size_t)e * 128 + c0];
        int dn = dst[e];
        float* op = &out[(size_t)dn * 128 + c0];
        #pragma unroll
        for (int j = 0; j < 8; j++) {
            float y = fmaxf(fmaf(av[j], bf2f((unsigned short)hv[j]), cv[j]), 0.f);
            if (y > 0.f) atomicAdd(&op[j], y);
        }
    }
}

// ---------------------------------------------------------------------------
extern "C" void kernel_launch(void* const* d_in, const int* in_sizes, int n_in,
                              void* d_out, int out_size, void* d_ws, size_t ws_size,
                              hipStream_t stream)
{
    const float* x   = (const float*)d_in[0];
    const int*   ei  = (const int*)d_in[1];
    const float* W1  = (const float*)d_in[2];
    // d_in[3] = b1: unused (BN shift-invariance)
    const float* g1  = (const float*)d_in[4];
    const float* be1 = (const float*)d_in[5];
    const float* W2  = (const float*)d_in[6];
    // d_in[7] = b2: unused
    const float* g2  = (const float*)d_in[8];
    const float* be2 = (const float*)d_in[9];
    float* out = (float*)d_out;

    int Nn = in_sizes[0] / 128;
    int E  = in_sizes[1] / 2;
    const int* srcI = ei;
    const int* dstI = ei + E;

    float* ws    = (float*)d_ws;
    float* gsum1 = ws;        float* gsq1 = ws + 128;
    float* gsum2 = ws + 256;  float* gsq2 = ws + 384;
    float* a1    = ws + 512;  float* c1   = ws + 640;
    float* a2    = ws + 768;  float* c2   = ws + 896;
    unsigned short* W2bf = (unsigned short*)(ws + 1024);   // 16384 ushort = 8192 floats
    float* P     = ws + 9216;
    unsigned short* h2 = (unsigned short*)(P + (size_t)Nn * 256);
    size_t need_mat = (size_t)9216 * 4 + (size_t)Nn * 256 * 4 + (size_t)E * 128 * 2;
    bool mat = (ws_size >= need_mat);

    hipMemsetAsync(ws, 0, 512 * sizeof(float), stream);
    hipMemsetAsync(out, 0, (size_t)out_size * sizeof(float), stream);

    dim3 b256(256);
    convert_w2_kernel<<<64, b256, 0, stream>>>(W2, W2bf);
    gemm_p_kernel<<<dim3((Nn + 63) / 64, 4), b256, 0, stream>>>(x, W1, P, Nn);
    stats1_kernel<<<4096, b256, 0, stream>>>(P, srcI, dstI, E, gsum1, gsq1);
    finalize_kernel<<<1, 128, 0, stream>>>(gsum1, gsq1, g1, be1, 1.0f / (float)E, a1, c1);

    int gE = (E + 63) / 64;
    if (mat) {
        edge_mfma_kernel<0><<<gE, b256, 0, stream>>>(P, srcI, dstI, W2bf, a1, c1,
            h2, gsum2, gsq2, nullptr, nullptr, nullptr, E);
        finalize_kernel<<<1, 128, 0, stream>>>(gsum2, gsq2, g2, be2, 1.0f / (float)E, a2, c2);
        scatter_kernel<<<4096, b256, 0, stream>>>(h2, dstI, a2, c2, out, E);
    } else {
        edge_mfma_kernel<1><<<gE, b256, 0, stream>>>(P, srcI, dstI, W2bf, a1, c1,
            nullptr, gsum2, gsq2, nullptr, nullptr, nullptr, E);
        finalize_kernel<<<1, 128, 0, stream>>>(gsum2, gsq2, g2, be2, 1.0f / (float)E, a2, c2);
        edge_mfma_kernel<2><<<gE, b256, 0, stream>>>(P, srcI, dstI, W2bf, a1, c1,
            nullptr, nullptr, nullptr, a2, c2, out, E);
    }
}

// Round 8
// 824.458 us; speedup vs baseline: 3.3874x; 3.2618x over previous
//
#include <hip/hip_runtime.h>
#include <stdint.h>

#define EPS 1e-5f

typedef __attribute__((ext_vector_type(4))) float f32x4;
typedef __attribute__((ext_vector_type(8))) short bf16x8_t;

__device__ __forceinline__ unsigned short f2bf(float x) {
    unsigned u = __float_as_uint(x);
    unsigned r = (u + 0x7FFFu + ((u >> 16) & 1u)) >> 16;
    return (unsigned short)r;
}
__device__ __forceinline__ float bf2f(unsigned short b) {
    return __uint_as_float(((unsigned)b) << 16);
}

// ---------------------------------------------------------------------------
// K0: P[N x 256] = x[N x 128] @ Wc^T ; Wc[j] = (j<128) ? W1[j][0:128] : W1[j-128][128:256]
// ---------------------------------------------------------------------------
__global__ __launch_bounds__(256) void gemm_p_kernel(const float* __restrict__ x,
    const float* __restrict__ W1, float* __restrict__ P, int Nn)
{
    __shared__ float As[64][36];
    __shared__ float Bt[32][68];
    int tid = threadIdx.x;
    int tx = tid & 15, ty = tid >> 4;
    int m0 = blockIdx.x * 64;
    int n0 = blockIdx.y * 64;
    float acc[4][4] = {};
    for (int kc = 0; kc < 128; kc += 32) {
        for (int t = tid; t < 512; t += 256) {
            int r = t >> 3, q = t & 7;
            int m = m0 + r;
            float4 v = make_float4(0.f, 0.f, 0.f, 0.f);
            if (m < Nn) v = *(const float4*)&x[(size_t)m * 128 + kc + q * 4];
            *(float4*)&As[r][q * 4] = v;
        }
        for (int t = tid; t < 512; t += 256) {
            int r = t >> 3, q = t & 7;
            int j = n0 + r;
            const float* s = (j < 128) ? &W1[(size_t)j * 256 + kc + q * 4]
                                       : &W1[(size_t)(j - 128) * 256 + 128 + kc + q * 4];
            float4 w = *(const float4*)s;
            Bt[q * 4 + 0][r] = w.x; Bt[q * 4 + 1][r] = w.y;
            Bt[q * 4 + 2][r] = w.z; Bt[q * 4 + 3][r] = w.w;
        }
        __syncthreads();
        #pragma unroll
        for (int kk = 0; kk < 32; kk += 4) {
            float avf[4][4];
            #pragma unroll
            for (int i = 0; i < 4; i++)
                *(float4*)&avf[i][0] = *(const float4*)&As[ty * 4 + i][kk];
            #pragma unroll
            for (int s = 0; s < 4; s++) {
                float4 b = *(const float4*)&Bt[kk + s][tx * 4];
                float bb[4] = {b.x, b.y, b.z, b.w};
                #pragma unroll
                for (int i = 0; i < 4; i++)
                    #pragma unroll
                    for (int j = 0; j < 4; j++)
                        acc[i][j] = fmaf(avf[i][s], bb[j], acc[i][j]);
            }
        }
        __syncthreads();
    }
    #pragma unroll
    for (int i = 0; i < 4; i++) {
        int m = m0 + ty * 4 + i;
        if (m < Nn)
            *(float4*)&P[(size_t)m * 256 + n0 + tx * 4] =
                make_float4(acc[i][0], acc[i][1], acc[i][2], acc[i][3]);
    }
}

// ---------------------------------------------------------------------------
__global__ void convert_w2_kernel(const float* __restrict__ W2, unsigned short* __restrict__ W2bf)
{
    int i = blockIdx.x * 256 + threadIdx.x;
    W2bf[i] = f2bf(W2[i]);
}

// ---------------------------------------------------------------------------
// K1: BN1 stats of h1[e][c] = Ps[src[e]][c] + Pd[dst[e]][c]
// ---------------------------------------------------------------------------
__global__ __launch_bounds__(256) void stats1_kernel(const float* __restrict__ P,
    const int* __restrict__ src, const int* __restrict__ dst, int E,
    float* __restrict__ gsum, float* __restrict__ gsq)
{
    int tid = threadIdx.x;
    int cg = tid & 31, rg = tid >> 5;
    int c0 = cg * 4;
    f32x4 s = {0.f, 0.f, 0.f, 0.f}, q = {0.f, 0.f, 0.f, 0.f};
    int stride = gridDim.x * 8;
    for (int e = blockIdx.x * 8 + rg; e < E; e += stride) {
        int sN = src[e], dN = dst[e];
        f32x4 v = *(const f32x4*)&P[(size_t)sN * 256 + c0]
                + *(const f32x4*)&P[(size_t)dN * 256 + 128 + c0];
        s += v; q += v * v;
    }
    __shared__ float shs[8][128], shq[8][128];
    *(f32x4*)&shs[rg][c0] = s;
    *(f32x4*)&shq[rg][c0] = q;
    __syncthreads();
    if (tid < 128) {
        float ts = 0.f, tq = 0.f;
        #pragma unroll
        for (int g = 0; g < 8; g++) { ts += shs[g][tid]; tq += shq[g][tid]; }
        atomicAdd(&gsum[tid], ts);
        atomicAdd(&gsq[tid], tq);
    }
}

// ---------------------------------------------------------------------------
__global__ void finalize_kernel(const float* __restrict__ gsum, const float* __restrict__ gsq,
    const float* __restrict__ gamma, const float* __restrict__ beta, float Einv,
    float* __restrict__ a, float* __restrict__ cc)
{
    int c = threadIdx.x;
    float mean = gsum[c] * Einv;
    float var  = gsq[c] * Einv - mean * mean;
    float ai = gamma[c] / sqrtf(var + EPS);
    a[c] = ai;
    cc[c] = beta[c] - mean * ai;
}

// ---------------------------------------------------------------------------
// Counting sort by dst: histogram, 3-dispatch exclusive scan -> offs[]
// ---------------------------------------------------------------------------
__global__ __launch_bounds__(256) void hist_kernel(const int* __restrict__ dst, int E,
    int* __restrict__ cnt)
{
    int i = blockIdx.x * 256 + threadIdx.x;
    int stride = gridDim.x * 256;
    for (; i < E; i += stride) atomicAdd(&cnt[dst[i]], 1);
}

__global__ __launch_bounds__(256) void scan_sum_kernel(const int* __restrict__ cnt, int Nn,
    int* __restrict__ bsum)
{
    int t = threadIdx.x, b = blockIdx.x;
    int i = b * 256 + t;
    __shared__ int sh[256];
    sh[t] = (i < Nn) ? cnt[i] : 0;
    __syncthreads();
    for (int d = 128; d > 0; d >>= 1) { if (t < d) sh[t] += sh[t + d]; __syncthreads(); }
    if (t == 0) bsum[b] = sh[0];
}

__global__ __launch_bounds__(256) void scan_base_kernel(const int* __restrict__ bsum, int nb,
    int* __restrict__ bbase)
{
    int t = threadIdx.x;
    int v = (t < nb) ? bsum[t] : 0;
    __shared__ int sh[256];
    sh[t] = v;
    __syncthreads();
    for (int d = 1; d < 256; d <<= 1) {
        int x = (t >= d) ? sh[t - d] : 0;
        __syncthreads();
        sh[t] += x;
        __syncthreads();
    }
    if (t < nb) bbase[t] = sh[t] - v;   // exclusive
}

__global__ __launch_bounds__(256) void scan_offs_kernel(const int* __restrict__ cnt,
    const int* __restrict__ bbase, int Nn, int E, int* __restrict__ offs)
{
    int t = threadIdx.x, b = blockIdx.x;
    int i = b * 256 + t;
    int v = (i < Nn) ? cnt[i] : 0;
    __shared__ int sh[256];
    sh[t] = v;
    __syncthreads();
    for (int d = 1; d < 256; d <<= 1) {
        int x = (t >= d) ? sh[t - d] : 0;
        __syncthreads();
        sh[t] += x;
        __syncthreads();
    }
    if (i < Nn) offs[i] = bbase[b] + sh[t] - v;
    if (i == 0 && b == 0) offs[Nn] = E;
}

// ---------------------------------------------------------------------------
// K3: MFMA edge GEMM2 (unchanged math). MODE 0 writes each edge's h2 row
// at its dst-sorted slot (offs[d] + pos[d]++) so the reducer streams segments.
// MODE 1: stats only.  MODE 2: BN2+ReLU+atomic scatter (fallback).
// ---------------------------------------------------------------------------
template<int MODE>
__global__ __launch_bounds__(256) void edge_mfma_kernel(
    const float* __restrict__ P, const int* __restrict__ src, const int* __restrict__ dst,
    const unsigned short* __restrict__ W2bf,
    const float* __restrict__ a1, const float* __restrict__ c1,
    unsigned short* __restrict__ h2s, float* __restrict__ gsum, float* __restrict__ gsq,
    const int* __restrict__ offs, int* __restrict__ pos,
    const float* __restrict__ a2, const float* __restrict__ c2,
    float* __restrict__ out, int E)
{
    int tid = threadIdx.x;
    int wid = tid >> 6, lane = tid & 63;
    int lr = lane & 15, lk = lane >> 4;        // A row / B col = lr, k-group = lk
    int wm = wid >> 1, wn = wid & 1;
    int e0 = blockIdx.x * 64;
    int m0w = wm * 32, n0w = wn * 64;

    __shared__ int rks[64];                    // MODE 0: sorted slot per tile row
    __shared__ int didx[64];                   // MODE 2: dst per tile row
    if (MODE == 0 && tid < 64) {
        int e = e0 + tid;
        if (e < E) {
            int d = dst[e];
            rks[tid] = offs[d] + atomicAdd(&pos[d], 1);
        }
    }
    if (MODE == 2 && tid < 64) {
        int e = min(e0 + tid, E - 1);
        didx[tid] = dst[e];
    }

    int e_mi[2], s_mi[2], d_mi[2];
    #pragma unroll
    for (int mi = 0; mi < 2; mi++) {
        int e = e0 + m0w + mi * 16 + lr;
        e_mi[mi] = e;
        int ec = min(e, E - 1);
        s_mi[mi] = src[ec];
        d_mi[mi] = dst[ec];
    }

    f32x4 acc[2][4];
    #pragma unroll
    for (int mi = 0; mi < 2; mi++)
        #pragma unroll
        for (int nj = 0; nj < 4; nj++) {
            f32x4 z = {0.f, 0.f, 0.f, 0.f};
            acc[mi][nj] = z;
        }

    #pragma unroll
    for (int kt = 0; kt < 4; kt++) {
        int c0 = kt * 32 + lk * 8;
        bf16x8_t b[4];
        #pragma unroll
        for (int nj = 0; nj < 4; nj++)
            b[nj] = *(const bf16x8_t*)&W2bf[(size_t)(n0w + nj * 16 + lr) * 128 + c0];
        f32x4 a1v0 = *(const f32x4*)&a1[c0], a1v1 = *(const f32x4*)&a1[c0 + 4];
        f32x4 c1v0 = *(const f32x4*)&c1[c0], c1v1 = *(const f32x4*)&c1[c0 + 4];
        #pragma unroll
        for (int mi = 0; mi < 2; mi++) {
            const float* ps = &P[(size_t)s_mi[mi] * 256 + c0];
            const float* pd = &P[(size_t)d_mi[mi] * 256 + 128 + c0];
            f32x4 h0 = *(const f32x4*)ps + *(const f32x4*)pd;
            f32x4 h1 = *(const f32x4*)(ps + 4) + *(const f32x4*)(pd + 4);
            float vm = (e_mi[mi] < E) ? 1.f : 0.f;
            bf16x8_t ahi, alo;
            #pragma unroll
            for (int j = 0; j < 8; j++) {
                float hv = (j < 4) ? h0[j] : h1[j - 4];
                float av = (j < 4) ? a1v0[j] : a1v1[j - 4];
                float cv = (j < 4) ? c1v0[j] : c1v1[j - 4];
                float u = fmaxf(fmaf(av, hv, cv), 0.f) * vm;
                unsigned short uh = f2bf(u);
                ahi[j] = (short)uh;
                alo[j] = (short)f2bf(u - bf2f(uh));
            }
            #pragma unroll
            for (int nj = 0; nj < 4; nj++) {
                acc[mi][nj] = __builtin_amdgcn_mfma_f32_16x16x32_bf16(ahi, b[nj], acc[mi][nj], 0, 0, 0);
                acc[mi][nj] = __builtin_amdgcn_mfma_f32_16x16x32_bf16(alo, b[nj], acc[mi][nj], 0, 0, 0);
            }
        }
    }
    // D layout (m89-verified): col = lane&15 (=lr), row = lk*4 + reg.

    if (MODE == 0 || MODE == 1) {
        __shared__ float reds[2][128], redq[2][128];
        #pragma unroll
        for (int nj = 0; nj < 4; nj++) {
            float sa = 0.f, sq = 0.f;
            #pragma unroll
            for (int mi = 0; mi < 2; mi++)
                #pragma unroll
                for (int r = 0; r < 4; r++) {
                    float v = acc[mi][nj][r];
                    sa += v; sq += v * v;
                }
            sa += __shfl_xor(sa, 16); sa += __shfl_xor(sa, 32);
            sq += __shfl_xor(sq, 16); sq += __shfl_xor(sq, 32);
            if (lk == 0) {
                reds[wm][n0w + nj * 16 + lr] = sa;
                redq[wm][n0w + nj * 16 + lr] = sq;
            }
        }
        if (MODE == 0) {
            __shared__ unsigned short ush[64][136];
            #pragma unroll
            for (int mi = 0; mi < 2; mi++)
                #pragma unroll
                for (int nj = 0; nj < 4; nj++)
                    #pragma unroll
                    for (int r = 0; r < 4; r++)
                        ush[m0w + mi * 16 + lk * 4 + r][n0w + nj * 16 + lr] = f2bf(acc[mi][nj][r]);
            __syncthreads();   // covers ush, reds/redq, rks
            if (tid < 128) {
                atomicAdd(&gsum[tid], reds[0][tid] + reds[1][tid]);
                atomicAdd(&gsq[tid],  redq[0][tid] + redq[1][tid]);
            }
            // 64 rows x 16 bf16x8 chunks = 1024 chunks; write each row at its sorted slot
            #pragma unroll
            for (int it = 0; it < 4; it++) {
                int chunk = it * 256 + tid;
                int row = chunk >> 4, q = chunk & 15;
                bf16x8_t v = *(const bf16x8_t*)&ush[row][q * 8];
                if (e0 + row < E)
                    *(bf16x8_t*)&h2s[(size_t)rks[row] * 128 + q * 8] = v;
            }
        } else {
            __syncthreads();
            if (tid < 128) {
                atomicAdd(&gsum[tid], reds[0][tid] + reds[1][tid]);
                atomicAdd(&gsq[tid],  redq[0][tid] + redq[1][tid]);
            }
        }
    }
    if (MODE == 2) {
        __syncthreads();   // didx visible
        float a2v[4], c2v[4];
        #pragma unroll
        for (int nj = 0; nj < 4; nj++) {
            int col = n0w + nj * 16 + lr;
            a2v[nj] = a2[col]; c2v[nj] = c2[col];
        }
        #pragma unroll
        for (int mi = 0; mi < 2; mi++)
            #pragma unroll
            for (int r = 0; r < 4; r++) {
                int row = m0w + mi * 16 + lk * 4 + r;
                if (e0 + row < E) {
                    int dn = didx[row];
                    #pragma unroll
                    for (int nj = 0; nj < 4; nj++) {
                        float y = fmaxf(fmaf(a2v[nj], acc[mi][nj][r], c2v[nj]), 0.f);
                        if (y > 0.f) atomicAdd(&out[(size_t)dn * 128 + n0w + nj * 16 + lr], y);
                    }
                }
            }
    }
}

// ---------------------------------------------------------------------------
// K5: segmented reduction. One wave per node: stream rows offs[n]..offs[n+1],
// y = relu(a2*h + c2), accumulate in registers, single clean store. NO atomics.
// Lane = 2 channels; per-row load = 64 lanes x 4B = 256B fully coalesced.
// ---------------------------------------------------------------------------
__global__ __launch_bounds__(256) void segred_kernel(const unsigned short* __restrict__ h2s,
    const int* __restrict__ offs, const float* __restrict__ a2, const float* __restrict__ c2,
    float* __restrict__ out, int Nn)
{
    int node = blockIdx.x * 4 + (threadIdx.x >> 6);
    if (node >= Nn) return;
    int lane = threadIdx.x & 63;
    int c0 = lane * 2;
    float aa0 = a2[c0], aa1 = a2[c0 + 1];
    float cb0 = c2[c0], cb1 = c2[c0 + 1];
    int rb = offs[node], re = offs[node + 1];
    float s0 = 0.f, s1 = 0.f;
    for (int r = rb; r < re; ++r) {
        unsigned v = *(const unsigned*)&h2s[(size_t)r * 128 + c0];
        s0 += fmaxf(fmaf(aa0, bf2f((unsigned short)(v & 0xffffu)), cb0), 0.f);
        s1 += fmaxf(fmaf(aa1, bf2f((unsigned short)(v >> 16)), cb1), 0.f);
    }
    *(float2*)&out[(size_t)node * 128 + c0] = make_float2(s0, s1);
}

// ---------------------------------------------------------------------------
extern "C" void kernel_launch(void* const* d_in, const int* in_sizes, int n_in,
                              void* d_out, int out_size, void* d_ws, size_t ws_size,
                              hipStream_t stream)
{
    const float* x   = (const float*)d_in[0];
    const int*   ei  = (const int*)d_in[1];
    const float* W1  = (const float*)d_in[2];
    // d_in[3] = b1: unused (BN shift-invariance)
    const float* g1  = (const float*)d_in[4];
    const float* be1 = (const float*)d_in[5];
    const float* W2  = (const float*)d_in[6];
    // d_in[7] = b2: unused
    const float* g2  = (const float*)d_in[8];
    const float* be2 = (const float*)d_in[9];
    float* out = (float*)d_out;

    int Nn = in_sizes[0] / 128;
    int E  = in_sizes[1] / 2;
    const int* srcI = ei;
    const int* dstI = ei + E;

    float* ws    = (float*)d_ws;
    float* gsum1 = ws;        float* gsq1 = ws + 128;
    float* gsum2 = ws + 256;  float* gsq2 = ws + 384;
    float* a1    = ws + 512;  float* c1   = ws + 640;
    float* a2    = ws + 768;  float* c2   = ws + 896;
    unsigned short* W2bf = (unsigned short*)(ws + 1024);   // 16384 ushort = 8192 floats
    float* P     = ws + 9216;
    unsigned short* h2s = (unsigned short*)(P + (size_t)Nn * 256);   // 16B-aligned
    int* cnt  = (int*)(h2s + (size_t)E * 128);
    int* pos  = cnt + Nn;
    int* offs = pos + Nn;          // Nn+1
    int* bsum = offs + Nn + 1;     // 256
    int* bbase = bsum + 256;       // 256
    size_t need_mat = (size_t)9216 * 4 + (size_t)Nn * 1024 + (size_t)E * 256
                    + ((size_t)3 * Nn + 513 + 512) * 4;
    bool mat = (ws_size >= need_mat);
    int nb = (Nn + 255) / 256;     // scan blocks (196 for N=50k; must be <=256)

    hipMemsetAsync(ws, 0, 512 * sizeof(float), stream);                 // stats accum
    hipMemsetAsync(out, 0, (size_t)out_size * sizeof(float), stream);

    dim3 b256(256);
    convert_w2_kernel<<<64, b256, 0, stream>>>(W2, W2bf);
    gemm_p_kernel<<<dim3((Nn + 63) / 64, 4), b256, 0, stream>>>(x, W1, P, Nn);
    stats1_kernel<<<4096, b256, 0, stream>>>(P, srcI, dstI, E, gsum1, gsq1);
    finalize_kernel<<<1, 128, 0, stream>>>(gsum1, gsq1, g1, be1, 1.0f / (float)E, a1, c1);

    int gE = (E + 63) / 64;
    if (mat && nb <= 256) {
        hipMemsetAsync(cnt, 0, (size_t)2 * Nn * sizeof(int), stream);   // cnt + pos
        hist_kernel<<<1024, b256, 0, stream>>>(dstI, E, cnt);
        scan_sum_kernel<<<nb, b256, 0, stream>>>(cnt, Nn, bsum);
        scan_base_kernel<<<1, b256, 0, stream>>>(bsum, nb, bbase);
        scan_offs_kernel<<<nb, b256, 0, stream>>>(cnt, bbase, Nn, E, offs);
        edge_mfma_kernel<0><<<gE, b256, 0, stream>>>(P, srcI, dstI, W2bf, a1, c1,
            h2s, gsum2, gsq2, offs, pos, nullptr, nullptr, nullptr, E);
        finalize_kernel<<<1, 128, 0, stream>>>(gsum2, gsq2, g2, be2, 1.0f / (float)E, a2, c2);
        segred_kernel<<<(Nn + 3) / 4, b256, 0, stream>>>(h2s, offs, a2, c2, out, Nn);
    } else {
        edge_mfma_kernel<1><<<gE, b256, 0, stream>>>(P, srcI, dstI, W2bf, a1, c1,
            nullptr, gsum2, gsq2, nullptr, nullptr, nullptr, nullptr, nullptr, E);
        finalize_kernel<<<1, 128, 0, stream>>>(gsum2, gsq2, g2, be2, 1.0f / (float)E, a2, c2);
        edge_mfma_kernel<2><<<gE, b256, 0, stream>>>(P, srcI, dstI, W2bf, a1, c1,
            nullptr, nullptr, nullptr, nullptr, nullptr, a2, c2, out, E);
    }
}